// Round 1
// baseline (464.213 us; speedup 1.0000x reference)
//
#include <hip/hip_runtime.h>
#include <hip/hip_bf16.h>
#include <math.h>

#define BS 2048   // B*S tokens
#define H  1024
#define E  8
#define F  512

// GEMM tiling
#define TM 64
#define TN 64
#define TK 16
#define APAD 4    // As[TK][TM+APAD]; +4 keeps float4 LDS reads 16B-aligned, breaks write conflicts

// ws layout (bytes):
//      0: counters: valid[8], mismatch[8], gcount[8]  (24 ints)
//   4096: sel      int2[BS]      (16 KB)
//  20480: wsel     float2[BS]    (16 KB)
//  36864: tok_list int[E*BS]     (64 KB)
// 102400: w_list   float[E*BS]   (64 KB)
// 167936: act      float[BS*2*F] (8 MB)   -- compact: sum of per-expert counts <= 4096 rows

__global__ __launch_bounds__(256) void zero_kernel(float* __restrict__ out, int* __restrict__ counters) {
    int idx = blockIdx.x * 256 + threadIdx.x;
    if (idx < 24) counters[idx] = 0;
    float4 z = make_float4(0.f, 0.f, 0.f, 0.f);
    size_t n4 = (size_t)BS * H / 4;
    for (size_t i = idx; i < n4; i += (size_t)gridDim.x * 256) ((float4*)out)[i] = z;
}

__global__ __launch_bounds__(256) void router_kernel(
    const float* __restrict__ x, const float* __restrict__ gate_w,
    const int* __restrict__ tok_mod, const int* __restrict__ exp_mod,
    int* __restrict__ counters, int2* __restrict__ sel_out, float2* __restrict__ w_out)
{
    __shared__ float gw[E][H];   // 32 KB
    int tid = threadIdx.x;
    const float4* gsrc = (const float4*)gate_w;
    float4* gdst = (float4*)&gw[0][0];
    for (int i = tid; i < E * H / 4; i += 256) gdst[i] = gsrc[i];
    __syncthreads();

    int wave = tid >> 6, lane = tid & 63;
    int token = blockIdx.x * 4 + wave;   // grid = BS/4, always in range

    float acc[E];
#pragma unroll
    for (int e = 0; e < E; e++) acc[e] = 0.f;
    const float* xr = x + (size_t)token * H;
    for (int h = lane; h < H; h += 64) {
        float xv = xr[h];
#pragma unroll
        for (int e = 0; e < E; e++) acc[e] += xv * gw[e][h];
    }
#pragma unroll
    for (int e = 0; e < E; e++) {
#pragma unroll
        for (int off = 32; off > 0; off >>= 1) acc[e] += __shfl_down(acc[e], off, 64);
    }
    if (lane == 0) {
        float m = acc[0];
#pragma unroll
        for (int e = 1; e < E; e++) m = fmaxf(m, acc[e]);
        float p[E]; float s = 0.f;
#pragma unroll
        for (int e = 0; e < E; e++) { p[e] = expf(acc[e] - m); s += p[e]; }
        float inv = 1.f / s;
#pragma unroll
        for (int e = 0; e < E; e++) p[e] *= inv;
        // top-2, ties -> lowest index (matches jax.lax.top_k)
        int i0 = 0; float p0 = p[0];
#pragma unroll
        for (int e = 1; e < E; e++) if (p[e] > p0) { p0 = p[e]; i0 = e; }
        int i1 = -1; float p1 = -1.f;
#pragma unroll
        for (int e = 0; e < E; e++) if (e != i0 && p[e] > p1) { p1 = p[e]; i1 = e; }
        float rs = 1.f / (p0 + p1);
        float w0 = p0 * rs, w1 = p1 * rs;

        int tm = tok_mod[token];
        int em0 = exp_mod[i0], em1 = exp_mod[i1];
        bool v0 = (tm != 0) && (em0 != 0);
        bool v1 = (tm != 0) && (em1 != 0);
        bool mm0 = v0 && (tm * em0 == -1);
        bool mm1 = v1 && (tm * em1 == -1);
        if (v0)  atomicAdd(&counters[i0], 1);
        if (v1)  atomicAdd(&counters[i1], 1);
        if (mm0) atomicAdd(&counters[8 + i0], 1);
        if (mm1) atomicAdd(&counters[8 + i1], 1);
        sel_out[token] = make_int2(i0, i1);
        w_out[token] = make_float2(w0, w1);
    }
}

__global__ __launch_bounds__(256) void finalize_kernel(
    const int* __restrict__ exp_mod, int* __restrict__ counters,
    const int2* __restrict__ sel_in, const float2* __restrict__ w_in,
    int* __restrict__ tok_list, float* __restrict__ w_list)
{
    int t = blockIdx.x * 256 + threadIdx.x;
    if (t >= BS) return;
    bool skip[E];
#pragma unroll
    for (int e = 0; e < E; e++) {
        int vc = counters[e], mc = counters[8 + e];
        skip[e] = (vc > 0) && (mc == vc) && (exp_mod[e] != 0);
    }
    int2 sel = sel_in[t];
    float2 w = w_in[t];
    float w0 = skip[sel.x] ? 0.f : w.x;
    float w1 = skip[sel.y] ? 0.f : w.y;
    float s = w0 + w1;
    if (s > 0.f) { float inv = 1.f / fmaxf(s, 1e-9f); w0 *= inv; w1 *= inv; }
    if (w0 > 0.f) {
        int pos = atomicAdd(&counters[16 + sel.x], 1);
        tok_list[sel.x * BS + pos] = t; w_list[sel.x * BS + pos] = w0;
    }
    if (w1 > 0.f) {
        int pos = atomicAdd(&counters[16 + sel.y], 1);
        tok_list[sel.y * BS + pos] = t; w_list[sel.y * BS + pos] = w1;
    }
}

// act[base_e + r][f] = silu(g) * u for gathered rows of expert e
__global__ __launch_bounds__(256) void gu_silu_kernel(
    const float* __restrict__ x, const float* __restrict__ gup,
    const int* __restrict__ counters, const int* __restrict__ tok_list,
    float* __restrict__ act)
{
    int e = blockIdx.z;
    int n = counters[16 + e];
    int t0 = blockIdx.y * TM;
    if (t0 >= n) return;
    int f0 = blockIdx.x * TN;
    int base = 0;
#pragma unroll
    for (int i = 0; i < E; i++) if (i < e) base += counters[16 + i];

    __shared__ float As[TK][TM + APAD];
    __shared__ float Bg[TK][TN];
    __shared__ float Bu[TK][TN];

    int tid = threadIdx.x;
    int tx = tid & 15, ty = tid >> 4;
    // A staging: one float4 of one gathered x row per thread
    int lrow = tid >> 2, lk = (tid & 3) << 2;
    int arow = min(t0 + lrow, n - 1);
    int tokA = tok_list[e * BS + arow];
    const float* xrow = x + (size_t)tokA * H + lk;
    // B staging: one float4 per thread per half
    int brow = tid >> 4, bcol = (tid & 15) << 2;
    const float* gbase = gup + ((size_t)e << 20) + (size_t)brow * 1024 + f0 + bcol;

    float accg[4][4] = {{0.f}};
    float accu[4][4] = {{0.f}};

    for (int k0 = 0; k0 < H; k0 += TK) {
        float4 av = *(const float4*)(xrow + k0);
        float4 bg = *(const float4*)(gbase + (size_t)k0 * 1024);
        float4 bu = *(const float4*)(gbase + (size_t)k0 * 1024 + 512);
        __syncthreads();
        As[lk + 0][lrow] = av.x; As[lk + 1][lrow] = av.y;
        As[lk + 2][lrow] = av.z; As[lk + 3][lrow] = av.w;
        *(float4*)&Bg[brow][bcol] = bg;
        *(float4*)&Bu[brow][bcol] = bu;
        __syncthreads();
#pragma unroll
        for (int kk = 0; kk < TK; kk++) {
            float4 a = *(const float4*)&As[kk][ty << 2];
            float4 g = *(const float4*)&Bg[kk][tx << 2];
            float4 u = *(const float4*)&Bu[kk][tx << 2];
            float aa[4] = {a.x, a.y, a.z, a.w};
            float gg[4] = {g.x, g.y, g.z, g.w};
            float uu[4] = {u.x, u.y, u.z, u.w};
#pragma unroll
            for (int i = 0; i < 4; i++)
#pragma unroll
                for (int j = 0; j < 4; j++) {
                    accg[i][j] += aa[i] * gg[j];
                    accu[i][j] += aa[i] * uu[j];
                }
        }
    }
#pragma unroll
    for (int i = 0; i < 4; i++) {
        int r = t0 + (ty << 2) + i;
        if (r < n) {
            float4 o; float* op = (float*)&o;
#pragma unroll
            for (int j = 0; j < 4; j++) {
                float g = accg[i][j], u = accu[i][j];
                op[j] = (g / (1.f + expf(-g))) * u;   // silu(g) * u
            }
            *(float4*)&act[(size_t)(base + r) * F + f0 + (tx << 2)] = o;
        }
    }
}

// out[token] += w * act_row @ down[e]; rows pre-scaled by w at LDS staging
__global__ __launch_bounds__(256) void down_scatter_kernel(
    const float* __restrict__ act, const float* __restrict__ down,
    const int* __restrict__ counters, const int* __restrict__ tok_list,
    const float* __restrict__ w_list, float* __restrict__ out)
{
    int e = blockIdx.z;
    int n = counters[16 + e];
    int t0 = blockIdx.y * TM;
    if (t0 >= n) return;
    int h0 = blockIdx.x * TN;
    int base = 0;
#pragma unroll
    for (int i = 0; i < E; i++) if (i < e) base += counters[16 + i];

    __shared__ float As[TK][TM + APAD];
    __shared__ float Bs[TK][TN];

    int tid = threadIdx.x;
    int tx = tid & 15, ty = tid >> 4;
    int lrow = tid >> 2, lk = (tid & 3) << 2;
    int arow = min(t0 + lrow, n - 1);
    float wrow = w_list[e * BS + arow];
    const float* arp = act + (size_t)(base + arow) * F + lk;
    int brow = tid >> 4, bcol = (tid & 15) << 2;
    const float* dbase = down + (size_t)e * F * H + (size_t)brow * H + h0 + bcol;

    float acc[4][4] = {{0.f}};

    for (int k0 = 0; k0 < F; k0 += TK) {
        float4 av = *(const float4*)(arp + k0);
        float4 bv = *(const float4*)(dbase + (size_t)k0 * H);
        __syncthreads();
        As[lk + 0][lrow] = av.x * wrow; As[lk + 1][lrow] = av.y * wrow;
        As[lk + 2][lrow] = av.z * wrow; As[lk + 3][lrow] = av.w * wrow;
        *(float4*)&Bs[brow][bcol] = bv;
        __syncthreads();
#pragma unroll
        for (int kk = 0; kk < TK; kk++) {
            float4 a = *(const float4*)&As[kk][ty << 2];
            float4 b = *(const float4*)&Bs[kk][tx << 2];
            float aa[4] = {a.x, a.y, a.z, a.w};
            float bb[4] = {b.x, b.y, b.z, b.w};
#pragma unroll
            for (int i = 0; i < 4; i++)
#pragma unroll
                for (int j = 0; j < 4; j++) acc[i][j] += aa[i] * bb[j];
        }
    }
#pragma unroll
    for (int i = 0; i < 4; i++) {
        int r = t0 + (ty << 2) + i;
        if (r < n) {
            int tok = tok_list[e * BS + r];
            float* orow = out + (size_t)tok * H + h0 + (tx << 2);
#pragma unroll
            for (int j = 0; j < 4; j++) atomicAdd(&orow[j], acc[i][j]);
        }
    }
}

extern "C" void kernel_launch(void* const* d_in, const int* in_sizes, int n_in,
                              void* d_out, int out_size, void* d_ws, size_t ws_size,
                              hipStream_t stream)
{
    const float* x       = (const float*)d_in[0];   // [2,1024,1024]
    const float* gate_w  = (const float*)d_in[1];   // [8,1024]
    const float* gup     = (const float*)d_in[2];   // [8,1024,1024]
    const float* down    = (const float*)d_in[3];   // [8,512,1024]
    const int*   tok_mod = (const int*)d_in[4];     // [2048]
    const int*   exp_mod = (const int*)d_in[5];     // [8]
    float* out = (float*)d_out;

    char* ws = (char*)d_ws;
    int*    counters = (int*)ws;
    int2*   sel      = (int2*)(ws + 4096);
    float2* wsel     = (float2*)(ws + 20480);
    int*    tok_list = (int*)(ws + 36864);
    float*  w_list   = (float*)(ws + 102400);
    float*  act      = (float*)(ws + 167936);

    zero_kernel<<<BS * H / 4 / 256, 256, 0, stream>>>(out, counters);
    router_kernel<<<BS / 4, 256, 0, stream>>>(x, gate_w, tok_mod, exp_mod, counters, sel, wsel);
    finalize_kernel<<<BS / 256, 256, 0, stream>>>(exp_mod, counters, sel, wsel, tok_list, w_list);
    dim3 g3(F / TN, BS / TM, E);
    gu_silu_kernel<<<g3, 256, 0, stream>>>(x, gup, counters, tok_list, act);
    dim3 g4(H / TN, BS / TM, E);
    down_scatter_kernel<<<g4, 256, 0, stream>>>(act, down, counters, tok_list, w_list, out);
}

// Round 2
// 214.045 us; speedup vs baseline: 2.1688x; 2.1688x over previous
//
#include <hip/hip_runtime.h>
#include <math.h>

#define BS 2048   // B*S tokens
#define H  1024
#define E  8
#define F  512

typedef __attribute__((ext_vector_type(8))) short bf16x8;
typedef __attribute__((ext_vector_type(4))) float f32x4;
typedef unsigned short u16;
typedef unsigned int u32;

#define LDK 40    // LDS row stride in u16 for BK=32 tiles: 32 k + 8 pad = 80 B (2-way max conflict)
#define BK  32

__device__ inline u16 f2bf(float f) {
    u32 u = __float_as_uint(f);
    return (u16)((u + 0x7fffu + ((u >> 16) & 1u)) >> 16);
}

// ws layout (bytes):
//        0: counters: valid[8], mismatch[8], gcount[8]
//     4096: sel      int2[BS]
//    20480: wsel     float2[BS]
//    36864: tok_list int[E*BS]
//   102400: w_list   float[E*BS]
//   167936: x_bf     u16[BS*H]            (4 MB)
//  4362240: gup_t    u16[E*1024*1024]     (16 MB)  [e][f-col][h-k] transposed bf16
// 21139456: down_t   u16[E*1024*512]      (8 MB)   [e][h-col][f-k] transposed bf16
// 29528064: act      u16[4096*F]          (4 MB)   w-scaled silu(g)*u, bf16

__global__ __launch_bounds__(256) void zero_kernel(float* __restrict__ out, int* __restrict__ counters) {
    int idx = blockIdx.x * 256 + threadIdx.x;
    if (idx < 24) counters[idx] = 0;
    float4 z = make_float4(0.f, 0.f, 0.f, 0.f);
    size_t n4 = (size_t)BS * H / 4;
    for (size_t i = idx; i < n4; i += (size_t)gridDim.x * 256) ((float4*)out)[i] = z;
}

__global__ __launch_bounds__(256) void convert_x_kernel(const float* __restrict__ x, u16* __restrict__ xb) {
    int idx = blockIdx.x * 256 + threadIdx.x;     // 8 floats per thread, 2M total
    const float4* s = (const float4*)x;
    float4 a = s[2 * idx], b = s[2 * idx + 1];
    uint4 q;
    q.x = (u32)f2bf(a.x) | ((u32)f2bf(a.y) << 16);
    q.y = (u32)f2bf(a.z) | ((u32)f2bf(a.w) << 16);
    q.z = (u32)f2bf(b.x) | ((u32)f2bf(b.y) << 16);
    q.w = (u32)f2bf(b.z) | ((u32)f2bf(b.w) << 16);
    ((uint4*)xb)[idx] = q;
}

// gup[e][k=h][n=f2] fp32 -> gup_t[e][n][k] bf16, 64x64 LDS tile transpose
__global__ __launch_bounds__(256) void transpose_gup_kernel(const float* __restrict__ g, u16* __restrict__ gt) {
    int e = blockIdx.z, k0 = blockIdx.x * 64, n0 = blockIdx.y * 64;
    __shared__ float t[64][68];
    int tid = threadIdx.x;
    int r = tid >> 2, c4 = tid & 3;
    const float* src = g + (size_t)e * 1048576 + (size_t)(k0 + r) * 1024 + n0 + c4 * 16;
#pragma unroll
    for (int i = 0; i < 4; i++) {
        float4 v = *(const float4*)(src + i * 4);
        *(float4*)&t[r][c4 * 16 + i * 4] = v;
    }
    __syncthreads();
    int nr = r, kc = c4;
    u16 o[16];
#pragma unroll
    for (int m = 0; m < 16; m++) o[m] = f2bf(t[kc * 16 + m][nr]);
    u16* dst = gt + (size_t)e * 1048576 + (size_t)(n0 + nr) * 1024 + k0 + kc * 16;
    uint4 q0, q1;
    q0.x = (u32)o[0] | ((u32)o[1] << 16);  q0.y = (u32)o[2] | ((u32)o[3] << 16);
    q0.z = (u32)o[4] | ((u32)o[5] << 16);  q0.w = (u32)o[6] | ((u32)o[7] << 16);
    q1.x = (u32)o[8] | ((u32)o[9] << 16);  q1.y = (u32)o[10] | ((u32)o[11] << 16);
    q1.z = (u32)o[12] | ((u32)o[13] << 16); q1.w = (u32)o[14] | ((u32)o[15] << 16);
    *(uint4*)dst = q0;
    *(uint4*)(dst + 8) = q1;
}

// down[e][k=f][n=h] fp32 -> down_t[e][n][k] bf16
__global__ __launch_bounds__(256) void transpose_down_kernel(const float* __restrict__ d, u16* __restrict__ dt) {
    int e = blockIdx.z, k0 = blockIdx.x * 64, n0 = blockIdx.y * 64;
    __shared__ float t[64][68];
    int tid = threadIdx.x;
    int r = tid >> 2, c4 = tid & 3;
    const float* src = d + (size_t)e * 524288 + (size_t)(k0 + r) * 1024 + n0 + c4 * 16;
#pragma unroll
    for (int i = 0; i < 4; i++) {
        float4 v = *(const float4*)(src + i * 4);
        *(float4*)&t[r][c4 * 16 + i * 4] = v;
    }
    __syncthreads();
    int nr = r, kc = c4;
    u16 o[16];
#pragma unroll
    for (int m = 0; m < 16; m++) o[m] = f2bf(t[kc * 16 + m][nr]);
    u16* dst = dt + (size_t)e * 524288 + (size_t)(n0 + nr) * 512 + k0 + kc * 16;
    uint4 q0, q1;
    q0.x = (u32)o[0] | ((u32)o[1] << 16);  q0.y = (u32)o[2] | ((u32)o[3] << 16);
    q0.z = (u32)o[4] | ((u32)o[5] << 16);  q0.w = (u32)o[6] | ((u32)o[7] << 16);
    q1.x = (u32)o[8] | ((u32)o[9] << 16);  q1.y = (u32)o[10] | ((u32)o[11] << 16);
    q1.z = (u32)o[12] | ((u32)o[13] << 16); q1.w = (u32)o[14] | ((u32)o[15] << 16);
    *(uint4*)dst = q0;
    *(uint4*)(dst + 8) = q1;
}

__global__ __launch_bounds__(256) void router_kernel(
    const float* __restrict__ x, const float* __restrict__ gate_w,
    const int* __restrict__ tok_mod, const int* __restrict__ exp_mod,
    int* __restrict__ counters, int2* __restrict__ sel_out, float2* __restrict__ w_out)
{
    __shared__ float gw[E][H];   // 32 KB
    int tid = threadIdx.x;
    for (int i = tid; i < E * H / 4; i += 256)
        ((float4*)&gw[0][0])[i] = ((const float4*)gate_w)[i];
    __syncthreads();
    int wv = tid >> 6, lane = tid & 63;
    for (int t = 0; t < 2; t++) {
        int token = blockIdx.x * 8 + wv * 2 + t;   // grid = BS/8
        float acc[E];
#pragma unroll
        for (int e = 0; e < E; e++) acc[e] = 0.f;
        const float* xr = x + (size_t)token * H;
        for (int h = lane; h < H; h += 64) {
            float xv = xr[h];
#pragma unroll
            for (int e = 0; e < E; e++) acc[e] += xv * gw[e][h];
        }
#pragma unroll
        for (int e = 0; e < E; e++) {
#pragma unroll
            for (int off = 32; off > 0; off >>= 1) acc[e] += __shfl_down(acc[e], off, 64);
        }
        if (lane == 0) {
            float m = acc[0];
#pragma unroll
            for (int e = 1; e < E; e++) m = fmaxf(m, acc[e]);
            float p[E]; float s = 0.f;
#pragma unroll
            for (int e = 0; e < E; e++) { p[e] = expf(acc[e] - m); s += p[e]; }
            float inv = 1.f / s;
#pragma unroll
            for (int e = 0; e < E; e++) p[e] *= inv;
            int i0 = 0; float p0 = p[0];
#pragma unroll
            for (int e = 1; e < E; e++) if (p[e] > p0) { p0 = p[e]; i0 = e; }
            int i1 = -1; float p1 = -1.f;
#pragma unroll
            for (int e = 0; e < E; e++) if (e != i0 && p[e] > p1) { p1 = p[e]; i1 = e; }
            float rs = 1.f / (p0 + p1);
            float w0 = p0 * rs, w1 = p1 * rs;
            int tm = tok_mod[token];
            int em0 = exp_mod[i0], em1 = exp_mod[i1];
            bool v0 = (tm != 0) && (em0 != 0);
            bool v1 = (tm != 0) && (em1 != 0);
            bool mm0 = v0 && (tm * em0 == -1);
            bool mm1 = v1 && (tm * em1 == -1);
            if (v0)  atomicAdd(&counters[i0], 1);
            if (v1)  atomicAdd(&counters[i1], 1);
            if (mm0) atomicAdd(&counters[8 + i0], 1);
            if (mm1) atomicAdd(&counters[8 + i1], 1);
            sel_out[token] = make_int2(i0, i1);
            w_out[token] = make_float2(w0, w1);
        }
    }
}

__global__ __launch_bounds__(256) void finalize_kernel(
    const int* __restrict__ exp_mod, int* __restrict__ counters,
    const int2* __restrict__ sel_in, const float2* __restrict__ w_in,
    int* __restrict__ tok_list, float* __restrict__ w_list)
{
    int t = blockIdx.x * 256 + threadIdx.x;
    if (t >= BS) return;
    bool skip[E];
#pragma unroll
    for (int e = 0; e < E; e++) {
        int vc = counters[e], mc = counters[8 + e];
        skip[e] = (vc > 0) && (mc == vc) && (exp_mod[e] != 0);
    }
    int2 sel = sel_in[t];
    float2 w = w_in[t];
    float w0 = skip[sel.x] ? 0.f : w.x;
    float w1 = skip[sel.y] ? 0.f : w.y;
    float s = w0 + w1;
    if (s > 0.f) { float inv = 1.f / fmaxf(s, 1e-9f); w0 *= inv; w1 *= inv; }
    if (w0 > 0.f) {
        int pos = atomicAdd(&counters[16 + sel.x], 1);
        tok_list[sel.x * BS + pos] = t; w_list[sel.x * BS + pos] = w0;
    }
    if (w1 > 0.f) {
        int pos = atomicAdd(&counters[16 + sel.y], 1);
        tok_list[sel.y * BS + pos] = t; w_list[sel.y * BS + pos] = w1;
    }
}

// MFMA gu: act[base+r][f] = bf16( w_r * silu(g) * u ), tile 128(m) x 64(f), BK=32
__global__ __launch_bounds__(256) void gu_mfma_kernel(
    const u16* __restrict__ xb, const u16* __restrict__ gup_t,
    const int* __restrict__ counters, const int* __restrict__ tok_list,
    const float* __restrict__ w_list, u16* __restrict__ act)
{
    int e = blockIdx.z;
    int n = counters[16 + e];
    int t0 = blockIdx.y * 128;
    if (t0 >= n) return;
    int f0 = blockIdx.x * 64;
    int base = 0;
#pragma unroll
    for (int i = 0; i < E; i++) if (i < e) base += counters[16 + i];

    __shared__ u16 Al[128 * LDK];   // 10240 B
    __shared__ u16 Bgl[64 * LDK];   //  5120 B
    __shared__ u16 Bul[64 * LDK];   //  5120 B

    int tid = threadIdx.x;
    // A staging: 512 16B-chunks (128 rows x 4), thread handles chunks tid and tid+256
    int ar0 = tid >> 2, akc0 = tid & 3;
    int ar1 = (tid + 256) >> 2, akc1 = tid & 3;
    int tok0 = tok_list[e * BS + min(t0 + ar0, n - 1)];
    int tok1 = tok_list[e * BS + min(t0 + ar1, n - 1)];
    const u16* ap0 = xb + (size_t)tok0 * H + akc0 * 8;
    const u16* ap1 = xb + (size_t)tok1 * H + akc1 * 8;
    // B staging: 256 chunks each (64 rows x 4)
    int br = tid >> 2, bkc = tid & 3;
    const u16* bgp = gup_t + ((size_t)e << 20) + (size_t)(f0 + br) * 1024 + bkc * 8;
    const u16* bup = gup_t + ((size_t)e << 20) + (size_t)(512 + f0 + br) * 1024 + bkc * 8;

    int wv = tid >> 6, lane = tid & 63;
    int l16 = lane & 15, quad = lane >> 4;
    int w32 = wv * 32;

    f32x4 accg[2][4], accu[2][4];
#pragma unroll
    for (int i = 0; i < 2; i++)
#pragma unroll
        for (int j = 0; j < 4; j++) {
            accg[i][j] = (f32x4){0.f, 0.f, 0.f, 0.f};
            accu[i][j] = (f32x4){0.f, 0.f, 0.f, 0.f};
        }

    for (int k0 = 0; k0 < H; k0 += BK) {
        uint4 va0 = *(const uint4*)(ap0 + k0);
        uint4 va1 = *(const uint4*)(ap1 + k0);
        uint4 vbg = *(const uint4*)(bgp + k0);
        uint4 vbu = *(const uint4*)(bup + k0);
        __syncthreads();
        *(uint4*)&Al[ar0 * LDK + akc0 * 8] = va0;
        *(uint4*)&Al[ar1 * LDK + akc1 * 8] = va1;
        *(uint4*)&Bgl[br * LDK + bkc * 8] = vbg;
        *(uint4*)&Bul[br * LDK + bkc * 8] = vbu;
        __syncthreads();
        bf16x8 af[2], bg[4], bu[4];
        af[0] = *(const bf16x8*)&Al[(w32 + l16) * LDK + quad * 8];
        af[1] = *(const bf16x8*)&Al[(w32 + 16 + l16) * LDK + quad * 8];
#pragma unroll
        for (int j = 0; j < 4; j++) {
            bg[j] = *(const bf16x8*)&Bgl[(j * 16 + l16) * LDK + quad * 8];
            bu[j] = *(const bf16x8*)&Bul[(j * 16 + l16) * LDK + quad * 8];
        }
#pragma unroll
        for (int i = 0; i < 2; i++)
#pragma unroll
            for (int j = 0; j < 4; j++) {
                accg[i][j] = __builtin_amdgcn_mfma_f32_16x16x32_bf16(af[i], bg[j], accg[i][j], 0, 0, 0);
                accu[i][j] = __builtin_amdgcn_mfma_f32_16x16x32_bf16(af[i], bu[j], accu[i][j], 0, 0, 0);
            }
    }
    // epilogue: C layout col=lane&15, row=quad*4+reg
    float wr[2][4];
#pragma unroll
    for (int i = 0; i < 2; i++)
#pragma unroll
        for (int r = 0; r < 4; r++) {
            int R = t0 + w32 + i * 16 + quad * 4 + r;
            wr[i][r] = (R < n) ? w_list[e * BS + R] : 0.f;
        }
#pragma unroll
    for (int i = 0; i < 2; i++)
#pragma unroll
        for (int j = 0; j < 4; j++)
#pragma unroll
            for (int r = 0; r < 4; r++) {
                int R = t0 + w32 + i * 16 + quad * 4 + r;
                if (R < n) {
                    float g = accg[i][j][r], u = accu[i][j][r];
                    float v = (g / (1.f + expf(-g))) * u * wr[i][r];
                    act[(size_t)(base + R) * F + f0 + j * 16 + l16] = f2bf(v);
                }
            }
}

// MFMA down: out[tok][h] += act_row @ down_t[e][h][:]  (w already folded into act)
__global__ __launch_bounds__(256) void down_mfma_kernel(
    const u16* __restrict__ act, const u16* __restrict__ down_t,
    const int* __restrict__ counters, const int* __restrict__ tok_list,
    float* __restrict__ out)
{
    int e = blockIdx.z;
    int n = counters[16 + e];
    int t0 = blockIdx.y * 128;
    if (t0 >= n) return;
    int h0 = blockIdx.x * 64;
    int base = 0;
#pragma unroll
    for (int i = 0; i < E; i++) if (i < e) base += counters[16 + i];

    __shared__ u16 Al[128 * LDK];
    __shared__ u16 Bl[64 * LDK];

    int tid = threadIdx.x;
    int ar0 = tid >> 2, akc0 = tid & 3;
    int ar1 = (tid + 256) >> 2, akc1 = tid & 3;
    const u16* ap0 = act + (size_t)(base + min(t0 + ar0, n - 1)) * F + akc0 * 8;
    const u16* ap1 = act + (size_t)(base + min(t0 + ar1, n - 1)) * F + akc1 * 8;
    int br = tid >> 2, bkc = tid & 3;
    const u16* bp = down_t + ((size_t)e << 19) + (size_t)(h0 + br) * 512 + bkc * 8;

    int wv = tid >> 6, lane = tid & 63;
    int l16 = lane & 15, quad = lane >> 4;
    int w32 = wv * 32;

    f32x4 acc[2][4];
#pragma unroll
    for (int i = 0; i < 2; i++)
#pragma unroll
        for (int j = 0; j < 4; j++) acc[i][j] = (f32x4){0.f, 0.f, 0.f, 0.f};

    for (int k0 = 0; k0 < F; k0 += BK) {
        uint4 va0 = *(const uint4*)(ap0 + k0);
        uint4 va1 = *(const uint4*)(ap1 + k0);
        uint4 vb  = *(const uint4*)(bp + k0);
        __syncthreads();
        *(uint4*)&Al[ar0 * LDK + akc0 * 8] = va0;
        *(uint4*)&Al[ar1 * LDK + akc1 * 8] = va1;
        *(uint4*)&Bl[br * LDK + bkc * 8] = vb;
        __syncthreads();
        bf16x8 af[2], bf[4];
        af[0] = *(const bf16x8*)&Al[(w32 + l16) * LDK + quad * 8];
        af[1] = *(const bf16x8*)&Al[(w32 + 16 + l16) * LDK + quad * 8];
#pragma unroll
        for (int j = 0; j < 4; j++)
            bf[j] = *(const bf16x8*)&Bl[(j * 16 + l16) * LDK + quad * 8];
#pragma unroll
        for (int i = 0; i < 2; i++)
#pragma unroll
            for (int j = 0; j < 4; j++)
                acc[i][j] = __builtin_amdgcn_mfma_f32_16x16x32_bf16(af[i], bf[j], acc[i][j], 0, 0, 0);
    }
    int tokr[2][4]; bool ok[2][4];
#pragma unroll
    for (int i = 0; i < 2; i++)
#pragma unroll
        for (int r = 0; r < 4; r++) {
            int R = t0 + w32 + i * 16 + quad * 4 + r;
            ok[i][r] = (R < n);
            tokr[i][r] = ok[i][r] ? tok_list[e * BS + R] : 0;
        }
#pragma unroll
    for (int i = 0; i < 2; i++)
#pragma unroll
        for (int j = 0; j < 4; j++)
#pragma unroll
            for (int r = 0; r < 4; r++)
                if (ok[i][r])
                    atomicAdd(&out[(size_t)tokr[i][r] * H + h0 + j * 16 + l16], acc[i][j][r]);
}

extern "C" void kernel_launch(void* const* d_in, const int* in_sizes, int n_in,
                              void* d_out, int out_size, void* d_ws, size_t ws_size,
                              hipStream_t stream)
{
    const float* x       = (const float*)d_in[0];
    const float* gate_w  = (const float*)d_in[1];
    const float* gup     = (const float*)d_in[2];
    const float* down    = (const float*)d_in[3];
    const int*   tok_mod = (const int*)d_in[4];
    const int*   exp_mod = (const int*)d_in[5];
    float* out = (float*)d_out;

    char* ws = (char*)d_ws;
    int*    counters = (int*)ws;
    int2*   sel      = (int2*)(ws + 4096);
    float2* wsel     = (float2*)(ws + 20480);
    int*    tok_list = (int*)(ws + 36864);
    float*  w_list   = (float*)(ws + 102400);
    u16*    x_bf     = (u16*)(ws + 167936);
    u16*    gup_t    = (u16*)(ws + 4362240);
    u16*    down_t   = (u16*)(ws + 21139456);
    u16*    act      = (u16*)(ws + 29528064);

    zero_kernel<<<2048, 256, 0, stream>>>(out, counters);
    convert_x_kernel<<<1024, 256, 0, stream>>>(x, x_bf);
    transpose_gup_kernel<<<dim3(16, 16, E), 256, 0, stream>>>(gup, gup_t);
    transpose_down_kernel<<<dim3(8, 16, E), 256, 0, stream>>>(down, down_t);
    router_kernel<<<BS / 8, 256, 0, stream>>>(x, gate_w, tok_mod, exp_mod, counters, sel, wsel);
    finalize_kernel<<<BS / 256, 256, 0, stream>>>(exp_mod, counters, sel, wsel, tok_list, w_list);
    gu_mfma_kernel<<<dim3(8, 16, E), 256, 0, stream>>>(x_bf, gup_t, counters, tok_list, w_list, act);
    down_mfma_kernel<<<dim3(16, 16, E), 256, 0, stream>>>(act, down_t, counters, tok_list, out);
}